// Round 2
// baseline (44127.194 us; speedup 1.0000x reference)
//
#include <hip/hip_runtime.h>
#include <cstdio>
#include <cstdint>

// V=30000, E=512, H=512, T=32, B=64, L=512
// eg layout: [t][b][e]       (64 MB)
// h  layout: [t][b][col]     (64 MB per dir)
// em layout: [t][b][tag]     (4 MB)
// wpack: [dir][wg:128][ks:8][sec:2][kc:16][r:16][j:4]  (16 MB)
//   sec 0 = W_ih (e-part), sec 1 = W_hh (h-part); k = ks*64 + kc*4 + j
//   r = gate*4 + col_local; global row = gate*512 + wg*4 + col_local

// ---------------------------------------------------------------------------
// K0: embedding gather -> eg[t][b][e]
// ---------------------------------------------------------------------------
__global__ __launch_bounds__(512) void k_gather(
    const int* __restrict__ x, const float* __restrict__ emb,
    float* __restrict__ eg)
{
    const int t   = blockIdx.x;
    const int tid = threadIdx.x;
    __shared__ int xv[64];
    if (tid < 64) xv[tid] = x[tid * 512 + t];
    __syncthreads();
    const int e4 = tid & 127;      // float4 index along e
    const int bq = tid >> 7;       // 0..3
    #pragma unroll
    for (int it = 0; it < 16; ++it) {
        const int b = it * 4 + bq;
        const float4 v = *reinterpret_cast<const float4*>(
            emb + (size_t)xv[b] * 512 + e4 * 4);
        *reinterpret_cast<float4*>(eg + ((size_t)t * 64 + b) * 512 + e4 * 4) = v;
    }
}

// ---------------------------------------------------------------------------
// K0b: pack weights into per-wave contiguous blocks for scalar loads
// ---------------------------------------------------------------------------
__global__ __launch_bounds__(256) void k_pack(
    const float* __restrict__ wih_f, const float* __restrict__ whh_f,
    const float* __restrict__ wih_b, const float* __restrict__ whh_b,
    float* __restrict__ wpack)
{
    const int i = blockIdx.x * 256 + threadIdx.x;   // 0 .. 4194303
    const int j   = i & 3;
    const int r   = (i >> 2) & 15;
    const int kc  = (i >> 6) & 15;
    const int sec = (i >> 10) & 1;
    const int ks  = (i >> 11) & 7;
    const int wg  = (i >> 14) & 127;
    const int dir = (i >> 21) & 1;
    const int k   = ks * 64 + kc * 4 + j;           // 0..511
    const int g   = r >> 2, cl = r & 3;
    const int rg  = g * 512 + wg * 4 + cl;          // global gate row
    const float* wih = dir ? wih_b : wih_f;
    const float* whh = dir ? whh_b : whh_f;
    const float v = sec ? whh[(size_t)rg * 512 + k] : wih[(size_t)rg * 512 + k];
    wpack[i] = v;
}

// ---------------------------------------------------------------------------
// K1: persistent BiLSTM recurrence. 256 WGs (128/dir) x 512 threads.
// WG owns 4 h-cols (16 gate rows). lane = b, wave = k-slice (split-k x8).
// Weights via scalar loads (wave-uniform); e/h via per-lane global loads.
// Device-scope atomic counter barrier per direction per step.
// ---------------------------------------------------------------------------
__global__ __launch_bounds__(512) void k_lstm(
    const float* __restrict__ eg, const float* __restrict__ wpack,
    const float* __restrict__ b_f, const float* __restrict__ b_b,
    float* __restrict__ h_f, float* __restrict__ h_b,
    int* __restrict__ bar)
{
    const int bid = blockIdx.x;
    const int dir = bid >> 7;
    const int wg  = bid & 127;
    float* HH       = dir ? h_b : h_f;
    const float* BS = dir ? b_b : b_f;
    int* ctr = bar + dir * 64;

    const int tid = threadIdx.x;
    const int b   = tid & 63;
    const int ks  = __builtin_amdgcn_readfirstlane(tid >> 6);

    __shared__ float part[8][16][64];   // 32 KB split-k exchange

    const float* wbase = wpack + (size_t)((dir * 128 + wg) * 8 + ks) * 2048;
    const float* wE = wbase;            // sec 0
    const float* wH = wbase + 1024;     // sec 1

    const int col = (tid >> 6) & 3;     // gate-phase column (tid<256)
    float bias4[4] = {0.f, 0.f, 0.f, 0.f};
    if (tid < 256) {
        #pragma unroll
        for (int g = 0; g < 4; ++g) bias4[g] = BS[g * 512 + wg * 4 + col];
    }
    float cst = 0.f;

    for (int s = 0; s < 512; ++s) {
        const int t = dir ? (511 - s) : s;
        float acc[16];
        #pragma unroll
        for (int r = 0; r < 16; ++r) acc[r] = 0.f;

        // ---- e-part: no dependency on h, runs before the barrier ----
        {
            const float* ep = eg + ((size_t)t * 64 + b) * 512 + ks * 64;
            #pragma unroll
            for (int half = 0; half < 2; ++half) {
                float4 ev[8];
                #pragma unroll
                for (int kc = 0; kc < 8; ++kc)
                    ev[kc] = *reinterpret_cast<const float4*>(ep + half * 32 + kc * 4);
                #pragma unroll
                for (int kc = 0; kc < 8; ++kc) {
                    const float* wp = wE + half * 512 + kc * 64;
                    #pragma unroll
                    for (int r = 0; r < 16; ++r) {
                        acc[r] = fmaf(wp[r * 4 + 0], ev[kc].x, acc[r]);
                        acc[r] = fmaf(wp[r * 4 + 1], ev[kc].y, acc[r]);
                        acc[r] = fmaf(wp[r * 4 + 2], ev[kc].z, acc[r]);
                        acc[r] = fmaf(wp[r * 4 + 3], ev[kc].w, acc[r]);
                    }
                }
            }
        }

        // ---- wait for h[t -/+ 1], then h-part ----
        if (s > 0) {
            if (tid == 0) {
                const int target = 128 * s;
                while (__hip_atomic_load(ctr, __ATOMIC_ACQUIRE,
                                         __HIP_MEMORY_SCOPE_AGENT) < target)
                    __builtin_amdgcn_s_sleep(2);
            }
            __syncthreads();
            const int tp = dir ? (t + 1) : (t - 1);
            const float* hp = HH + ((size_t)tp * 64 + b) * 512 + ks * 64;
            #pragma unroll
            for (int half = 0; half < 2; ++half) {
                float4 hv[8];
                #pragma unroll
                for (int kc = 0; kc < 8; ++kc)
                    hv[kc] = *reinterpret_cast<const float4*>(hp + half * 32 + kc * 4);
                #pragma unroll
                for (int kc = 0; kc < 8; ++kc) {
                    const float* wp = wH + half * 512 + kc * 64;
                    #pragma unroll
                    for (int r = 0; r < 16; ++r) {
                        acc[r] = fmaf(wp[r * 4 + 0], hv[kc].x, acc[r]);
                        acc[r] = fmaf(wp[r * 4 + 1], hv[kc].y, acc[r]);
                        acc[r] = fmaf(wp[r * 4 + 2], hv[kc].z, acc[r]);
                        acc[r] = fmaf(wp[r * 4 + 3], hv[kc].w, acc[r]);
                    }
                }
            }
        }

        // ---- split-k reduce + gates ----
        #pragma unroll
        for (int r = 0; r < 16; ++r) part[ks][r][b] = acc[r];
        __syncthreads();

        if (tid < 256) {
            float g4[4];
            #pragma unroll
            for (int g = 0; g < 4; ++g) {
                const int r = g * 4 + col;
                float v = bias4[g];
                #pragma unroll
                for (int w = 0; w < 8; ++w) v += part[w][r][b];
                g4[g] = v;
            }
            const float si = 1.f / (1.f + expf(-g4[0]));
            const float sf = 1.f / (1.f + expf(-g4[1]));
            const float tg = tanhf(g4[2]);
            const float so = 1.f / (1.f + expf(-g4[3]));
            cst = sf * cst + si * tg;
            const float hvv = so * tanhf(cst);
            HH[((size_t)t * 64 + b) * 512 + wg * 4 + col] = hvv;
        }

        if (s < 511) {
            __threadfence();
            __syncthreads();
            if (tid == 0)
                __hip_atomic_fetch_add(ctr, 1, __ATOMIC_RELEASE,
                                       __HIP_MEMORY_SCOPE_AGENT);
        }
    }
}

// ---------------------------------------------------------------------------
// K2: emissions  em[t][b][tag] = [hf[t][b][:]; hb[t][b][:]] . W[tag][:] + bias
// ---------------------------------------------------------------------------
__global__ __launch_bounds__(256) void k_em(
    const float* __restrict__ hf, const float* __restrict__ hb,
    const float* __restrict__ Wm, const float* __restrict__ bias,
    float* __restrict__ em)
{
    const int t   = blockIdx.x;
    const int tid = threadIdx.x;
    const int b   = tid & 63;
    const int tg  = tid >> 6;          // 0..3 -> tags [tg*8, tg*8+8)
    __shared__ float Wl[128][33];
    float acc[8] = {};

    for (int ch = 0; ch < 8; ++ch) {
        {
            const int tag = tid >> 3;   // 0..31
            const int kq  = tid & 7;    // 0..7
            const float* src = Wm + (size_t)tag * 1024 + ch * 128 + kq * 16;
            #pragma unroll
            for (int ii = 0; ii < 4; ++ii) {
                const float4 v = *reinterpret_cast<const float4*>(src + ii * 4);
                const int k0 = kq * 16 + ii * 4;
                Wl[k0 + 0][tag] = v.x; Wl[k0 + 1][tag] = v.y;
                Wl[k0 + 2][tag] = v.z; Wl[k0 + 3][tag] = v.w;
            }
        }
        __syncthreads();
        const float* hsrc = (ch < 4)
            ? (hf + ((size_t)t * 64 + b) * 512 + ch * 128)
            : (hb + ((size_t)t * 64 + b) * 512 + (ch - 4) * 128);
        #pragma unroll 4
        for (int kk = 0; kk < 128; kk += 4) {
            const float4 h4 = *reinterpret_cast<const float4*>(hsrc + kk);
            const float ha[4] = {h4.x, h4.y, h4.z, h4.w};
            #pragma unroll
            for (int j = 0; j < 4; ++j)
                #pragma unroll
                for (int jt = 0; jt < 8; ++jt)
                    acc[jt] = fmaf(ha[j], Wl[kk + j][tg * 8 + jt], acc[jt]);
        }
        __syncthreads();
    }

    #pragma unroll
    for (int jt = 0; jt < 8; ++jt) {
        const int tag = tg * 8 + jt;
        em[((size_t)t * 64 + b) * 32 + tag] = acc[jt] + bias[tag];
    }
}

// ---------------------------------------------------------------------------
// K3: Viterbi forward + backtrace, one wave per batch row.
// Matches reference order: (score + trans) + em, first-max argmax.
// ---------------------------------------------------------------------------
__global__ __launch_bounds__(64) void k_vit(
    const float* __restrict__ em, const float* __restrict__ startv,
    const float* __restrict__ endv, const float* __restrict__ trans,
    int* __restrict__ out)
{
    const int b    = blockIdx.x;
    const int lane = threadIdx.x;
    const int c    = lane & 31;
    const bool act = lane < 32;
    __shared__ unsigned char hist[511][32];
    __shared__ int outb[512];

    float tr[32];
    #pragma unroll 8
    for (int p = 0; p < 32; ++p) tr[p] = trans[p * 32 + c];

    float s = act ? (startv[c] + em[(size_t)b * 32 + c]) : -1e30f;

    for (int t = 1; t < 512; ++t) {
        const float emc = act ? em[((size_t)t * 64 + b) * 32 + c] : 0.f;
        float m = -1e30f; int arg = 0;
        #pragma unroll 8
        for (int p = 0; p < 32; ++p) {
            const float v = __shfl(s, p) + tr[p] + emc;   // (s+tr)+em, ref order
            if (v > m) { m = v; arg = p; }                // strict > => first max
        }
        if (act) { s = m; hist[t - 1][c] = (unsigned char)arg; }
    }

    s = act ? (s + endv[c]) : -1e30f;
    int idx = act ? c : 63;
    #pragma unroll
    for (int off = 32; off >= 1; off >>= 1) {
        const float om = __shfl_down(s, off);
        const int   oi = __shfl_down(idx, off);
        if (om > s || (om == s && oi < idx)) { s = om; idx = oi; }
    }
    idx = __shfl(idx, 0);

    if (lane == 0) {
        int tag = idx;
        outb[511] = tag;
        for (int t = 510; t >= 0; --t) { tag = hist[t][tag]; outb[t] = tag; }
    }
    __syncthreads();
    for (int i = lane; i < 512; i += 64) out[(size_t)b * 512 + i] = outb[i];
}

// ---------------------------------------------------------------------------
extern "C" void kernel_launch(void* const* d_in, const int* in_sizes, int n_in,
                              void* d_out, int out_size, void* d_ws, size_t ws_size,
                              hipStream_t stream)
{
    const int*   x      = (const int*)d_in[0];
    const float* emb    = (const float*)d_in[1];
    const float* w_ih_f = (const float*)d_in[2];
    const float* w_hh_f = (const float*)d_in[3];
    const float* b_f    = (const float*)d_in[4];
    const float* w_ih_b = (const float*)d_in[5];
    const float* w_hh_b = (const float*)d_in[6];
    const float* b_b    = (const float*)d_in[7];
    const float* Wm     = (const float*)d_in[8];
    const float* bvec   = (const float*)d_in[9];
    const float* startv = (const float*)d_in[10];
    const float* endv   = (const float*)d_in[11];
    const float* trans  = (const float*)d_in[12];
    int* out = (int*)d_out;

    float* ws    = (float*)d_ws;
    float* eg    = ws;                          // 16,777,216 f32 (64 MB)
    float* h_f   = ws + 16777216;               // 16,777,216 f32
    float* h_b   = ws + 33554432;               // 16,777,216 f32
    float* em    = ws + 50331648;               //  1,048,576 f32
    float* wpack = ws + 51380224;               //  4,194,304 f32 (16 MB)
    int*   bar   = (int*)(ws + 55574528);       //  128 ints

    const size_t need = (size_t)(55574528 + 128) * 4;
    if (ws_size < need) {
        fprintf(stderr, "kernel_launch: ws too small: %zu < %zu\n", ws_size, need);
        return;
    }

    (void)hipMemsetAsync(bar, 0, 512, stream);
    k_gather<<<dim3(512),   512, 0, stream>>>(x, emb, eg);
    k_pack  <<<dim3(16384), 256, 0, stream>>>(w_ih_f, w_hh_f, w_ih_b, w_hh_b, wpack);
    k_lstm  <<<dim3(256),   512, 0, stream>>>(eg, wpack, b_f, b_b, h_f, h_b, bar);
    k_em    <<<dim3(512),   256, 0, stream>>>(h_f, h_b, Wm, bvec, em);
    k_vit   <<<dim3(64),     64, 0, stream>>>(em, startv, endv, trans, out);
}

// Round 3
// 25648.318 us; speedup vs baseline: 1.7205x; 1.7205x over previous
//
#include <hip/hip_runtime.h>
#include <cstdio>
#include <cstdint>

// V=30000, E=512, H=512, T=32, B=64, L=512
// eg layout: [t][b][e]       (64 MB)
// h  layout: [t][b][col]     (64 MB per dir)
// em layout: [t][b][tag]     (4 MB)
// wpack: [dir][wg:128][ks:8][sec:2][kc:16][r:16][j:4]  (16 MB)
//   sec 0 = W_ih (e-part), sec 1 = W_hh (h-part); k = ks*64 + kc*4 + j
//   r = gate*4 + col_local; global row = gate*512 + wg*4 + col_local
// flags: [dir:2][wg:128] x 16-int stride (16 KB); producer wg sets flag=s+1
//   after its step-s h-slice is globally visible (relaxed agent stores +
//   vmcnt drain). No threadfence / RMW atomics / release fences in the loop.

// ---------------------------------------------------------------------------
// K0: embedding gather -> eg[t][b][e]
// ---------------------------------------------------------------------------
__global__ __launch_bounds__(512) void k_gather(
    const int* __restrict__ x, const float* __restrict__ emb,
    float* __restrict__ eg)
{
    const int t   = blockIdx.x;
    const int tid = threadIdx.x;
    __shared__ int xv[64];
    if (tid < 64) xv[tid] = x[tid * 512 + t];
    __syncthreads();
    const int e4 = tid & 127;      // float4 index along e
    const int bq = tid >> 7;       // 0..3
    #pragma unroll
    for (int it = 0; it < 16; ++it) {
        const int b = it * 4 + bq;
        const float4 v = *reinterpret_cast<const float4*>(
            emb + (size_t)xv[b] * 512 + e4 * 4);
        *reinterpret_cast<float4*>(eg + ((size_t)t * 64 + b) * 512 + e4 * 4) = v;
    }
}

// ---------------------------------------------------------------------------
// K0b: pack weights into per-wave contiguous blocks
// ---------------------------------------------------------------------------
__global__ __launch_bounds__(256) void k_pack(
    const float* __restrict__ wih_f, const float* __restrict__ whh_f,
    const float* __restrict__ wih_b, const float* __restrict__ whh_b,
    float* __restrict__ wpack)
{
    const int i = blockIdx.x * 256 + threadIdx.x;   // 0 .. 4194303
    const int j   = i & 3;
    const int r   = (i >> 2) & 15;
    const int kc  = (i >> 6) & 15;
    const int sec = (i >> 10) & 1;
    const int ks  = (i >> 11) & 7;
    const int wg  = (i >> 14) & 127;
    const int dir = (i >> 21) & 1;
    const int k   = ks * 64 + kc * 4 + j;           // 0..511
    const int g   = r >> 2, cl = r & 3;
    const int rg  = g * 512 + wg * 4 + cl;          // global gate row
    const float* wih = dir ? wih_b : wih_f;
    const float* whh = dir ? whh_b : whh_f;
    const float v = sec ? whh[(size_t)rg * 512 + k] : wih[(size_t)rg * 512 + k];
    wpack[i] = v;
}

// ---------------------------------------------------------------------------
// K1: persistent BiLSTM recurrence. 256 WGs (128/dir) x 512 threads.
// WG owns 4 h-cols (16 gate rows). lane = b, wave = k-slice (split-k x8).
// Cross-block sync: per-block flag slots, relaxed agent-scope ops only.
// ---------------------------------------------------------------------------
__global__ __launch_bounds__(512) void k_lstm(
    const float* __restrict__ eg, const float* __restrict__ wpack,
    const float* __restrict__ b_f, const float* __restrict__ b_b,
    float* __restrict__ h_f, float* __restrict__ h_b,
    int* __restrict__ bar)
{
    const int bid = blockIdx.x;
    const int dir = bid >> 7;
    const int wg  = bid & 127;
    float* HH       = dir ? h_b : h_f;
    const float* BS = dir ? b_b : b_f;
    int* flg = bar + dir * 2048;        // 128 slots x 16 ints (64 B apart)

    const int tid = threadIdx.x;
    const int b   = tid & 63;
    const int ks  = __builtin_amdgcn_readfirstlane(tid >> 6);

    __shared__ float part[8][16][64];   // 32 KB split-k exchange

    const float* wbase = wpack + (size_t)((dir * 128 + wg) * 8 + ks) * 2048;
    const float* wE = wbase;            // sec 0
    const float* wH = wbase + 1024;     // sec 1

    const int col = (tid >> 6) & 3;     // gate-phase column (tid<256)
    float bias4[4] = {0.f, 0.f, 0.f, 0.f};
    if (tid < 256) {
        #pragma unroll
        for (int g = 0; g < 4; ++g) bias4[g] = BS[g * 512 + wg * 4 + col];
    }
    float cst = 0.f;

    for (int s = 0; s < 512; ++s) {
        const int t = dir ? (511 - s) : s;
        float acc[16];
        #pragma unroll
        for (int r = 0; r < 16; ++r) acc[r] = 0.f;

        // ---- e-part: no dependency on h, runs before the flag wait ----
        {
            const float* ep = eg + ((size_t)t * 64 + b) * 512 + ks * 64;
            #pragma unroll
            for (int half = 0; half < 2; ++half) {
                float4 ev[8];
                #pragma unroll
                for (int kc = 0; kc < 8; ++kc)
                    ev[kc] = *reinterpret_cast<const float4*>(ep + half * 32 + kc * 4);
                #pragma unroll
                for (int kc = 0; kc < 8; ++kc) {
                    const float* wp = wE + half * 512 + kc * 64;
                    #pragma unroll
                    for (int r = 0; r < 16; ++r) {
                        acc[r] = fmaf(wp[r * 4 + 0], ev[kc].x, acc[r]);
                        acc[r] = fmaf(wp[r * 4 + 1], ev[kc].y, acc[r]);
                        acc[r] = fmaf(wp[r * 4 + 2], ev[kc].z, acc[r]);
                        acc[r] = fmaf(wp[r * 4 + 3], ev[kc].w, acc[r]);
                    }
                }
            }
        }

        // ---- wait for all 128 producers of step s-1 (parallel poll) ----
        if (s > 0) {
            if (tid < 128) {
                const int* fp = flg + tid * 16;
                while (__hip_atomic_load(fp, __ATOMIC_RELAXED,
                                         __HIP_MEMORY_SCOPE_AGENT) < s)
                    __builtin_amdgcn_s_sleep(1);
            }
            __syncthreads();

            const int tp = dir ? (t + 1) : (t - 1);
            const float* hp = HH + ((size_t)tp * 64 + b) * 512 + ks * 64;
            #pragma unroll
            for (int half = 0; half < 2; ++half) {
                float hv[32];
                #pragma unroll
                for (int k = 0; k < 32; ++k)
                    hv[k] = __hip_atomic_load(hp + half * 32 + k,
                                              __ATOMIC_RELAXED,
                                              __HIP_MEMORY_SCOPE_AGENT);
                #pragma unroll
                for (int kc = 0; kc < 8; ++kc) {
                    const float* wp = wH + half * 512 + kc * 64;
                    #pragma unroll
                    for (int r = 0; r < 16; ++r) {
                        acc[r] = fmaf(wp[r * 4 + 0], hv[kc * 4 + 0], acc[r]);
                        acc[r] = fmaf(wp[r * 4 + 1], hv[kc * 4 + 1], acc[r]);
                        acc[r] = fmaf(wp[r * 4 + 2], hv[kc * 4 + 2], acc[r]);
                        acc[r] = fmaf(wp[r * 4 + 3], hv[kc * 4 + 3], acc[r]);
                    }
                }
            }
        }

        // ---- split-k reduce + gates ----
        #pragma unroll
        for (int r = 0; r < 16; ++r) part[ks][r][b] = acc[r];
        __syncthreads();

        if (tid < 256) {
            float g4[4];
            #pragma unroll
            for (int g = 0; g < 4; ++g) {
                const int r = g * 4 + col;
                float v = bias4[g];
                #pragma unroll
                for (int w = 0; w < 8; ++w) v += part[w][r][b];
                g4[g] = v;
            }
            const float si = 1.f / (1.f + expf(-g4[0]));
            const float sf = 1.f / (1.f + expf(-g4[1]));
            const float tg = tanhf(g4[2]);
            const float so = 1.f / (1.f + expf(-g4[3]));
            cst = sf * cst + si * tg;
            const float hvv = so * tanhf(cst);
            // write-through, cache-bypassing store -> visible at coherence pt
            __hip_atomic_store(&HH[((size_t)t * 64 + b) * 512 + wg * 4 + col],
                               hvv, __ATOMIC_RELAXED, __HIP_MEMORY_SCOPE_AGENT);
        }

        if (s < 511) {
            // drain own stores, then block-wide rendezvous, then publish flag
            asm volatile("s_waitcnt vmcnt(0)" ::: "memory");
            __syncthreads();
            if (tid == 0)
                __hip_atomic_store(flg + wg * 16, s + 1,
                                   __ATOMIC_RELAXED, __HIP_MEMORY_SCOPE_AGENT);
        } else {
            __syncthreads();   // keep waves together before exit
        }
    }
}

// ---------------------------------------------------------------------------
// K2: emissions  em[t][b][tag] = [hf[t][b][:]; hb[t][b][:]] . W[tag][:] + bias
// ---------------------------------------------------------------------------
__global__ __launch_bounds__(256) void k_em(
    const float* __restrict__ hf, const float* __restrict__ hb,
    const float* __restrict__ Wm, const float* __restrict__ bias,
    float* __restrict__ em)
{
    const int t   = blockIdx.x;
    const int tid = threadIdx.x;
    const int b   = tid & 63;
    const int tg  = tid >> 6;          // 0..3 -> tags [tg*8, tg*8+8)
    __shared__ float Wl[128][33];
    float acc[8] = {};

    for (int ch = 0; ch < 8; ++ch) {
        {
            const int tag = tid >> 3;   // 0..31
            const int kq  = tid & 7;    // 0..7
            const float* src = Wm + (size_t)tag * 1024 + ch * 128 + kq * 16;
            #pragma unroll
            for (int ii = 0; ii < 4; ++ii) {
                const float4 v = *reinterpret_cast<const float4*>(src + ii * 4);
                const int k0 = kq * 16 + ii * 4;
                Wl[k0 + 0][tag] = v.x; Wl[k0 + 1][tag] = v.y;
                Wl[k0 + 2][tag] = v.z; Wl[k0 + 3][tag] = v.w;
            }
        }
        __syncthreads();
        const float* hsrc = (ch < 4)
            ? (hf + ((size_t)t * 64 + b) * 512 + ch * 128)
            : (hb + ((size_t)t * 64 + b) * 512 + (ch - 4) * 128);
        #pragma unroll 4
        for (int kk = 0; kk < 128; kk += 4) {
            const float4 h4 = *reinterpret_cast<const float4*>(hsrc + kk);
            const float ha[4] = {h4.x, h4.y, h4.z, h4.w};
            #pragma unroll
            for (int j = 0; j < 4; ++j)
                #pragma unroll
                for (int jt = 0; jt < 8; ++jt)
                    acc[jt] = fmaf(ha[j], Wl[kk + j][tg * 8 + jt], acc[jt]);
        }
        __syncthreads();
    }

    #pragma unroll
    for (int jt = 0; jt < 8; ++jt) {
        const int tag = tg * 8 + jt;
        em[((size_t)t * 64 + b) * 32 + tag] = acc[jt] + bias[tag];
    }
}

// ---------------------------------------------------------------------------
// K3: Viterbi forward + backtrace, one wave per batch row.
// Matches reference order: (score + trans) + em, first-max argmax.
// ---------------------------------------------------------------------------
__global__ __launch_bounds__(64) void k_vit(
    const float* __restrict__ em, const float* __restrict__ startv,
    const float* __restrict__ endv, const float* __restrict__ trans,
    int* __restrict__ out)
{
    const int b    = blockIdx.x;
    const int lane = threadIdx.x;
    const int c    = lane & 31;
    const bool act = lane < 32;
    __shared__ unsigned char hist[511][32];
    __shared__ int outb[512];

    float tr[32];
    #pragma unroll 8
    for (int p = 0; p < 32; ++p) tr[p] = trans[p * 32 + c];

    float s = act ? (startv[c] + em[(size_t)b * 32 + c]) : -1e30f;

    for (int t = 1; t < 512; ++t) {
        const float emc = act ? em[((size_t)t * 64 + b) * 32 + c] : 0.f;
        float m = -1e30f; int arg = 0;
        #pragma unroll 8
        for (int p = 0; p < 32; ++p) {
            const float v = __shfl(s, p) + tr[p] + emc;   // (s+tr)+em, ref order
            if (v > m) { m = v; arg = p; }                // strict > => first max
        }
        if (act) { s = m; hist[t - 1][c] = (unsigned char)arg; }
    }

    s = act ? (s + endv[c]) : -1e30f;
    int idx = act ? c : 63;
    #pragma unroll
    for (int off = 32; off >= 1; off >>= 1) {
        const float om = __shfl_down(s, off);
        const int   oi = __shfl_down(idx, off);
        if (om > s || (om == s && oi < idx)) { s = om; idx = oi; }
    }
    idx = __shfl(idx, 0);

    if (lane == 0) {
        int tag = idx;
        outb[511] = tag;
        for (int t = 510; t >= 0; --t) { tag = hist[t][tag]; outb[t] = tag; }
    }
    __syncthreads();
    for (int i = lane; i < 512; i += 64) out[(size_t)b * 512 + i] = outb[i];
}

// ---------------------------------------------------------------------------
extern "C" void kernel_launch(void* const* d_in, const int* in_sizes, int n_in,
                              void* d_out, int out_size, void* d_ws, size_t ws_size,
                              hipStream_t stream)
{
    const int*   x      = (const int*)d_in[0];
    const float* emb    = (const float*)d_in[1];
    const float* w_ih_f = (const float*)d_in[2];
    const float* w_hh_f = (const float*)d_in[3];
    const float* b_f    = (const float*)d_in[4];
    const float* w_ih_b = (const float*)d_in[5];
    const float* w_hh_b = (const float*)d_in[6];
    const float* b_b    = (const float*)d_in[7];
    const float* Wm     = (const float*)d_in[8];
    const float* bvec   = (const float*)d_in[9];
    const float* startv = (const float*)d_in[10];
    const float* endv   = (const float*)d_in[11];
    const float* trans  = (const float*)d_in[12];
    int* out = (int*)d_out;

    float* ws    = (float*)d_ws;
    float* eg    = ws;                          // 16,777,216 f32 (64 MB)
    float* h_f   = ws + 16777216;               // 16,777,216 f32
    float* h_b   = ws + 33554432;               // 16,777,216 f32
    float* em    = ws + 50331648;               //  1,048,576 f32
    float* wpack = ws + 51380224;               //  4,194,304 f32 (16 MB)
    int*   bar   = (int*)(ws + 55574528);       //  4096 ints (16 KB flags)

    const size_t need = (size_t)(55574528 + 4096) * 4;
    if (ws_size < need) {
        fprintf(stderr, "kernel_launch: ws too small: %zu < %zu\n", ws_size, need);
        return;
    }

    (void)hipMemsetAsync(bar, 0, 16384, stream);
    k_gather<<<dim3(512),   512, 0, stream>>>(x, emb, eg);
    k_pack  <<<dim3(16384), 256, 0, stream>>>(w_ih_f, w_hh_f, w_ih_b, w_hh_b, wpack);
    k_lstm  <<<dim3(256),   512, 0, stream>>>(eg, wpack, b_f, b_b, h_f, h_b, bar);
    k_em    <<<dim3(512),   256, 0, stream>>>(h_f, h_b, Wm, bvec, em);
    k_vit   <<<dim3(64),     64, 0, stream>>>(em, startv, endv, trans, out);
}

// Round 4
// 13888.763 us; speedup vs baseline: 3.1772x; 1.8467x over previous
//
#include <hip/hip_runtime.h>
#include <cstdio>
#include <cstdint>

// V=30000, E=512, H=512, T=32, B=64, L=512
// eg layout: [t][e][b]       (64 MB)   <- transposed for coalesced lane=b reads
// h  layout: [t][col][b]     (64 MB per dir)
// em layout: [t][b][tag]     (4 MB)
// wpack: [dir][wg:128][ks:8][sec:2][kc:16][r:16][j:4]  (16 MB)
//   sec 0 = W_ih (e-part), sec 1 = W_hh (h-part); k = ks*64 + kc*4 + j
//   r = gate*4 + col_local; global row = gate*512 + wg*4 + col_local
// flags: [dir:2][wg:128] x 16-int stride; producer wg sets flag=s+1 after its
//   step-s h-slice is globally visible (relaxed agent stores + vmcnt drain).

// ---------------------------------------------------------------------------
// K0: embedding gather -> eg[t][e][b]  (LDS transpose, padded tile)
// ---------------------------------------------------------------------------
__global__ __launch_bounds__(512) void k_gather(
    const int* __restrict__ x, const float* __restrict__ emb,
    float* __restrict__ eg)
{
    const int t   = blockIdx.x;
    const int tid = threadIdx.x;
    __shared__ int xv[64];
    __shared__ float tile[32][65];
    if (tid < 64) xv[tid] = x[tid * 512 + t];
    __syncthreads();

    const int bL = tid >> 3;        // 0..63 load-phase batch
    const int eq = tid & 7;         // 0..7  load-phase e-quad
    const int eS = tid >> 4;        // 0..31 store-phase e
    const int b4 = tid & 15;        // 0..15 store-phase b-quad

    for (int ec = 0; ec < 16; ++ec) {
        const float4 v = *reinterpret_cast<const float4*>(
            emb + (size_t)xv[bL] * 512 + ec * 32 + eq * 4);
        tile[eq * 4 + 0][bL] = v.x;
        tile[eq * 4 + 1][bL] = v.y;
        tile[eq * 4 + 2][bL] = v.z;
        tile[eq * 4 + 3][bL] = v.w;
        __syncthreads();
        float4 o;
        o.x = tile[eS][b4 * 4 + 0];
        o.y = tile[eS][b4 * 4 + 1];
        o.z = tile[eS][b4 * 4 + 2];
        o.w = tile[eS][b4 * 4 + 3];
        *reinterpret_cast<float4*>(
            eg + ((size_t)t * 512 + ec * 32 + eS) * 64 + b4 * 4) = o;
        __syncthreads();
    }
}

// ---------------------------------------------------------------------------
// K0b: pack weights into per-wave contiguous blocks
// ---------------------------------------------------------------------------
__global__ __launch_bounds__(256) void k_pack(
    const float* __restrict__ wih_f, const float* __restrict__ whh_f,
    const float* __restrict__ wih_b, const float* __restrict__ whh_b,
    float* __restrict__ wpack)
{
    const int i = blockIdx.x * 256 + threadIdx.x;   // 0 .. 4194303
    const int j   = i & 3;
    const int r   = (i >> 2) & 15;
    const int kc  = (i >> 6) & 15;
    const int sec = (i >> 10) & 1;
    const int ks  = (i >> 11) & 7;
    const int wg  = (i >> 14) & 127;
    const int dir = (i >> 21) & 1;
    const int k   = ks * 64 + kc * 4 + j;           // 0..511
    const int g   = r >> 2, cl = r & 3;
    const int rg  = g * 512 + wg * 4 + cl;          // global gate row
    const float* wih = dir ? wih_b : wih_f;
    const float* whh = dir ? whh_b : whh_f;
    const float v = sec ? whh[(size_t)rg * 512 + k] : wih[(size_t)rg * 512 + k];
    wpack[i] = v;
}

// ---------------------------------------------------------------------------
// K1: persistent BiLSTM recurrence. 256 WGs (128/dir) x 512 threads.
// WG owns 4 h-cols (16 gate rows). lane = b, wave = k-slice (split-k x8).
// All operand loads coalesced (lane=b, layouts [..][b]).
// ---------------------------------------------------------------------------
__global__ __launch_bounds__(512) void k_lstm(
    const float* __restrict__ eg, const float* __restrict__ wpack,
    const float* __restrict__ b_f, const float* __restrict__ b_b,
    float* __restrict__ h_f, float* __restrict__ h_b,
    int* __restrict__ bar)
{
    const int bid = blockIdx.x;
    const int dir = bid >> 7;
    const int wg  = bid & 127;
    float* HH       = dir ? h_b : h_f;
    const float* BS = dir ? b_b : b_f;
    int* flg = bar + dir * 2048;        // 128 slots x 16 ints (64 B apart)

    const int tid = threadIdx.x;
    const int b   = tid & 63;
    const int ks  = __builtin_amdgcn_readfirstlane(tid >> 6);

    __shared__ float part[8][16][64];   // 32 KB split-k exchange

    const float* wbase = wpack + (size_t)((dir * 128 + wg) * 8 + ks) * 2048;
    const float* wE = wbase;            // sec 0
    const float* wH = wbase + 1024;     // sec 1

    const int col = (tid >> 6) & 3;     // gate-phase column (tid<256)
    float bias4[4] = {0.f, 0.f, 0.f, 0.f};
    if (tid < 256) {
        #pragma unroll
        for (int g = 0; g < 4; ++g) bias4[g] = BS[g * 512 + wg * 4 + col];
    }
    float cst = 0.f;

    for (int s = 0; s < 512; ++s) {
        const int t = dir ? (511 - s) : s;
        float acc[16];
        #pragma unroll
        for (int r = 0; r < 16; ++r) acc[r] = 0.f;

        // ---- e-part: coalesced reads of eg[t][ks*64 + k][b] ----
        {
            const float* ep = eg + ((size_t)t * 512 + ks * 64) * 64 + b;
            #pragma unroll
            for (int half = 0; half < 2; ++half) {
                float ev[32];
                #pragma unroll
                for (int k = 0; k < 32; ++k)
                    ev[k] = ep[(half * 32 + k) * 64];
                #pragma unroll
                for (int kc = 0; kc < 8; ++kc) {
                    const float* wp = wE + half * 512 + kc * 64;
                    #pragma unroll
                    for (int r = 0; r < 16; ++r) {
                        acc[r] = fmaf(wp[r * 4 + 0], ev[kc * 4 + 0], acc[r]);
                        acc[r] = fmaf(wp[r * 4 + 1], ev[kc * 4 + 1], acc[r]);
                        acc[r] = fmaf(wp[r * 4 + 2], ev[kc * 4 + 2], acc[r]);
                        acc[r] = fmaf(wp[r * 4 + 3], ev[kc * 4 + 3], acc[r]);
                    }
                }
            }
        }

        // ---- wait for all 128 producers of step s-1 (parallel poll) ----
        if (s > 0) {
            if (tid < 128) {
                const int* fp = flg + tid * 16;
                while (__hip_atomic_load(fp, __ATOMIC_RELAXED,
                                         __HIP_MEMORY_SCOPE_AGENT) < s)
                    __builtin_amdgcn_s_sleep(1);
            }
            __syncthreads();

            const int tp = dir ? (t + 1) : (t - 1);
            const float* hp = HH + ((size_t)tp * 512 + ks * 64) * 64 + b;
            #pragma unroll
            for (int half = 0; half < 2; ++half) {
                float hv[32];
                #pragma unroll
                for (int k = 0; k < 32; ++k)
                    hv[k] = __hip_atomic_load(hp + (half * 32 + k) * 64,
                                              __ATOMIC_RELAXED,
                                              __HIP_MEMORY_SCOPE_AGENT);
                #pragma unroll
                for (int kc = 0; kc < 8; ++kc) {
                    const float* wp = wH + half * 512 + kc * 64;
                    #pragma unroll
                    for (int r = 0; r < 16; ++r) {
                        acc[r] = fmaf(wp[r * 4 + 0], hv[kc * 4 + 0], acc[r]);
                        acc[r] = fmaf(wp[r * 4 + 1], hv[kc * 4 + 1], acc[r]);
                        acc[r] = fmaf(wp[r * 4 + 2], hv[kc * 4 + 2], acc[r]);
                        acc[r] = fmaf(wp[r * 4 + 3], hv[kc * 4 + 3], acc[r]);
                    }
                }
            }
        }

        // ---- split-k reduce + gates ----
        #pragma unroll
        for (int r = 0; r < 16; ++r) part[ks][r][b] = acc[r];
        __syncthreads();

        if (tid < 256) {
            float g4[4];
            #pragma unroll
            for (int g = 0; g < 4; ++g) {
                const int r = g * 4 + col;
                float v = bias4[g];
                #pragma unroll
                for (int w = 0; w < 8; ++w) v += part[w][r][b];
                g4[g] = v;
            }
            const float si = 1.f / (1.f + expf(-g4[0]));
            const float sf = 1.f / (1.f + expf(-g4[1]));
            const float tg = tanhf(g4[2]);
            const float so = 1.f / (1.f + expf(-g4[3]));
            cst = sf * cst + si * tg;
            const float hvv = so * tanhf(cst);
            // coalesced (b contiguous) agent-scope store
            __hip_atomic_store(&HH[((size_t)t * 512 + wg * 4 + col) * 64 + b],
                               hvv, __ATOMIC_RELAXED, __HIP_MEMORY_SCOPE_AGENT);
        }

        if (s < 511) {
            asm volatile("s_waitcnt vmcnt(0)" ::: "memory");
            __syncthreads();
            if (tid == 0)
                __hip_atomic_store(flg + wg * 16, s + 1,
                                   __ATOMIC_RELAXED, __HIP_MEMORY_SCOPE_AGENT);
        } else {
            __syncthreads();
        }
    }
}

// ---------------------------------------------------------------------------
// K2: emissions  em[t][b][tag] = [hf;hb](t,b,:) . W[tag][:] + bias
// h layout [t][col][b]
// ---------------------------------------------------------------------------
__global__ __launch_bounds__(256) void k_em(
    const float* __restrict__ hf, const float* __restrict__ hb,
    const float* __restrict__ Wm, const float* __restrict__ bias,
    float* __restrict__ em)
{
    const int t   = blockIdx.x;
    const int tid = threadIdx.x;
    const int b   = tid & 63;
    const int tg  = tid >> 6;          // 0..3 -> tags [tg*8, tg*8+8)
    __shared__ float Wl[128][33];
    float acc[8] = {};

    for (int ch = 0; ch < 8; ++ch) {
        {
            const int tag = tid >> 3;   // 0..31
            const int kq  = tid & 7;    // 0..7
            const float* src = Wm + (size_t)tag * 1024 + ch * 128 + kq * 16;
            #pragma unroll
            for (int ii = 0; ii < 4; ++ii) {
                const float4 v = *reinterpret_cast<const float4*>(src + ii * 4);
                const int k0 = kq * 16 + ii * 4;
                Wl[k0 + 0][tag] = v.x; Wl[k0 + 1][tag] = v.y;
                Wl[k0 + 2][tag] = v.z; Wl[k0 + 3][tag] = v.w;
            }
        }
        __syncthreads();
        const float* hsrc = (ch < 4)
            ? (hf + ((size_t)t * 512 + ch * 128) * 64 + b)
            : (hb + ((size_t)t * 512 + (ch - 4) * 128) * 64 + b);
        #pragma unroll 4
        for (int kl = 0; kl < 128; ++kl) {
            const float hv = hsrc[kl * 64];       // coalesced across lanes
            #pragma unroll
            for (int jt = 0; jt < 8; ++jt)
                acc[jt] = fmaf(hv, Wl[kl][tg * 8 + jt], acc[jt]);
        }
        __syncthreads();
    }

    #pragma unroll
    for (int jt = 0; jt < 8; ++jt) {
        const int tag = tg * 8 + jt;
        em[((size_t)t * 64 + b) * 32 + tag] = acc[jt] + bias[tag];
    }
}

// ---------------------------------------------------------------------------
// K3: Viterbi forward + backtrace, one wave per batch row.
// Matches reference order: (score + trans) + em, first-max argmax.
// ---------------------------------------------------------------------------
__global__ __launch_bounds__(64) void k_vit(
    const float* __restrict__ em, const float* __restrict__ startv,
    const float* __restrict__ endv, const float* __restrict__ trans,
    int* __restrict__ out)
{
    const int b    = blockIdx.x;
    const int lane = threadIdx.x;
    const int c    = lane & 31;
    const bool act = lane < 32;
    __shared__ unsigned char hist[511][32];
    __shared__ int outb[512];

    float tr[32];
    #pragma unroll 8
    for (int p = 0; p < 32; ++p) tr[p] = trans[p * 32 + c];

    float s = act ? (startv[c] + em[(size_t)b * 32 + c]) : -1e30f;

    for (int t = 1; t < 512; ++t) {
        const float emc = act ? em[((size_t)t * 64 + b) * 32 + c] : 0.f;
        float m = -1e30f; int arg = 0;
        #pragma unroll 8
        for (int p = 0; p < 32; ++p) {
            const float v = __shfl(s, p) + tr[p] + emc;   // (s+tr)+em, ref order
            if (v > m) { m = v; arg = p; }                // strict > => first max
        }
        if (act) { s = m; hist[t - 1][c] = (unsigned char)arg; }
    }

    s = act ? (s + endv[c]) : -1e30f;
    int idx = act ? c : 63;
    #pragma unroll
    for (int off = 32; off >= 1; off >>= 1) {
        const float om = __shfl_down(s, off);
        const int   oi = __shfl_down(idx, off);
        if (om > s || (om == s && oi < idx)) { s = om; idx = oi; }
    }
    idx = __shfl(idx, 0);

    if (lane == 0) {
        int tag = idx;
        outb[511] = tag;
        for (int t = 510; t >= 0; --t) { tag = hist[t][tag]; outb[t] = tag; }
    }
    __syncthreads();
    for (int i = lane; i < 512; i += 64) out[(size_t)b * 512 + i] = outb[i];
}

// ---------------------------------------------------------------------------
extern "C" void kernel_launch(void* const* d_in, const int* in_sizes, int n_in,
                              void* d_out, int out_size, void* d_ws, size_t ws_size,
                              hipStream_t stream)
{
    const int*   x      = (const int*)d_in[0];
    const float* emb    = (const float*)d_in[1];
    const float* w_ih_f = (const float*)d_in[2];
    const float* w_hh_f = (const float*)d_in[3];
    const float* b_f    = (const float*)d_in[4];
    const float* w_ih_b = (const float*)d_in[5];
    const float* w_hh_b = (const float*)d_in[6];
    const float* b_b    = (const float*)d_in[7];
    const float* Wm     = (const float*)d_in[8];
    const float* bvec   = (const float*)d_in[9];
    const float* startv = (const float*)d_in[10];
    const float* endv   = (const float*)d_in[11];
    const float* trans  = (const float*)d_in[12];
    int* out = (int*)d_out;

    float* ws    = (float*)d_ws;
    float* eg    = ws;                          // 16,777,216 f32 (64 MB)
    float* h_f   = ws + 16777216;               // 16,777,216 f32
    float* h_b   = ws + 33554432;               // 16,777,216 f32
    float* em    = ws + 50331648;               //  1,048,576 f32
    float* wpack = ws + 51380224;               //  4,194,304 f32 (16 MB)
    int*   bar   = (int*)(ws + 55574528);       //  4096 ints (16 KB flags)

    const size_t need = (size_t)(55574528 + 4096) * 4;
    if (ws_size < need) {
        fprintf(stderr, "kernel_launch: ws too small: %zu < %zu\n", ws_size, need);
        return;
    }

    (void)hipMemsetAsync(bar, 0, 16384, stream);
    k_gather<<<dim3(512),   512, 0, stream>>>(x, emb, eg);
    k_pack  <<<dim3(16384), 256, 0, stream>>>(w_ih_f, w_hh_f, w_ih_b, w_hh_b, wpack);
    k_lstm  <<<dim3(256),   512, 0, stream>>>(eg, wpack, b_f, b_b, h_f, h_b, bar);
    k_em    <<<dim3(512),   256, 0, stream>>>(h_f, h_b, Wm, bvec, em);
    k_vit   <<<dim3(64),     64, 0, stream>>>(em, startv, endv, trans, out);
}